// Round 7
// baseline (21563.730 us; speedup 1.0000x reference)
//
#include <hip/hip_runtime.h>
#include <hip/hip_bf16.h>
#include <stdint.h>

// ---------------------------------------------------------------------------
// Two-stream GRU encoder, MI355X round 7.
//   Phase A (unchanged, ~1.0 ms): split-bf16 3-pass MFMA GEMM (fp32-accurate).
//   Phase B: persistent GRU. Round-6 refuted the spill theory (VGPR=128 with
//     (512,1) cap lifted, WRITE_SIZE shows no scratch writes). Remaining
//     common cause of 28 GB FETCH + 39us/step across rounds 3/4/6: the
//     32-lane relaxed uncached poll storm on one 1-KB flag region (self-
//     congesting: pollers throttle the L3 slices the release stores and h
//     stores must traverse). THIS ROUND: single-lane-per-WG counter sync
//     (RELEASE atomicAdd + RELAXED 1-lane poll + one ACQUIRE), 256-B-padded
//     per-group counters, s_sleep(8) poll quantum, skip sync at s=511.
// ---------------------------------------------------------------------------

#define Hh 512
#define Bb 64
#define Ss 512
#define M_TOT (Bb * Ss)   // 32768
#define K1d 2048
#define K0d 1536
#define NG 1536           // 3H
#define NF 1024           // 2H

// ---------------- ws layout (bytes) ----------------
#define WS_G_OFF    ((size_t)0)
#define WS_G_BYTES  ((size_t)M_TOT * NG * 4)                 // 201,326,592
#define WS_FLAGS_OFF (WS_G_OFF + WS_G_BYTES)                 // 8 counters, 64-int stride

typedef short short8 __attribute__((ext_vector_type(8)));
typedef float f32x4 __attribute__((ext_vector_type(4)));

__global__ void zero_flags_kernel(int* flags) { flags[threadIdx.x] = 0; }

// ---------------- split-bf16 MFMA GEMM ----------------
// 128x128 tile, BK=32, 256 threads (4 waves in 2x2), 4x4 16x16 frags/wave.
#define BM 128
#define BN 128
#define BK 32

// swizzled byte offset inside a [128][32] bf16 tile (row stride 64B):
// addr(r, kbyte) = (r*64 + kbyte) ^ ((r&7)<<4)   — bijective, conflict-free
__device__ __forceinline__ int lds_addr(int r, int kbyte) {
  return ((r << 6) + kbyte) ^ ((r & 7) << 4);
}

// stage 16 consecutive fp32 (one half-row) as bf16 hi/lo into LDS tiles
__device__ __forceinline__ void stage_half_row(const float* __restrict__ src,
                                               ushort* hbuf, ushort* lbuf,
                                               int r, int half) {
#pragma unroll
  for (int q = 0; q < 4; ++q) {
    const float4 v = *(const float4*)(src + q * 4);
    const float e[4] = {v.x, v.y, v.z, v.w};
    ushort4 hv, lv;
    ushort* hp = (ushort*)&hv;
    ushort* lp = (ushort*)&lv;
#pragma unroll
    for (int t = 0; t < 4; ++t) {
      const uint u = __float_as_uint(e[t]);
      const uint hb = u & 0xFFFF0000u;                 // truncated bf16 hi
      const float lf = e[t] - __uint_as_float(hb);     // exact residual
      hp[t] = (ushort)(u >> 16);
      lp[t] = (ushort)(__float_as_uint(lf) >> 16);     // truncated bf16 lo
    }
    const int boff = lds_addr(r, half * 32 + q * 8);
    *(ushort4*)((char*)hbuf + boff) = hv;
    *(ushort4*)((char*)lbuf + boff) = lv;
  }
}

__launch_bounds__(256)
__global__ void gemm_G(const float* __restrict__ A1,   // feats1 [32768][2048]
                       const float* __restrict__ A0,   // feats0 [32768][1536]
                       const float* __restrict__ W1,   // [1536][2048] row-major
                       const float* __restrict__ W0,   // [1024][1536] row-major
                       const float* __restrict__ b1v,
                       const float* __restrict__ b0v,
                       float* __restrict__ G) {
  __shared__ ushort AhL[BM * BK];   // 8 KB each
  __shared__ ushort AlL[BM * BK];
  __shared__ ushort BhL[BN * BK];
  __shared__ ushort BlL[BN * BK];

  // L3 supertile swizzle: 4 groups of 64 m-tiles x 12 n-tiles
  const int bid = blockIdx.x;            // 0..3071
  const int group = bid / 768;
  const int rem = bid - group * 768;
  const int n = rem / 64;                // 0..11
  const int mt = group * 64 + (rem & 63);
  const int m0 = mt * BM, n0 = n * BN;

  const int tid = threadIdx.x;
  const int wid = tid >> 6;              // wave 0..3
  const int wm = wid >> 1, wn = wid & 1; // 2x2 wave grid (64x64 per wave)
  const int lane = tid & 63;
  const int lr = lane & 15;              // frag row/col
  const int ks = lane >> 4;              // k-slot 0..3 (8 bf16 each)

  const int r_st = tid >> 1, half = tid & 1;   // staging map

  f32x4 acc[4][4];
#pragma unroll
  for (int i = 0; i < 4; ++i)
#pragma unroll
    for (int j = 0; j < 4; ++j) acc[i][j] = (f32x4){0.f, 0.f, 0.f, 0.f};

  const int nph = (n < 8) ? 2 : 1;       // n>=8 -> pure i_n cols (no feats0 term)

  for (int p = 0; p < nph; ++p) {
    const float* Ap = (p == 0) ? A1 : A0;
    const float* Wp = (p == 0) ? W1 : W0;
    const int K = (p == 0) ? K1d : K0d;

    for (int k0 = 0; k0 < K; k0 += BK) {
      __syncthreads();
      stage_half_row(Ap + (size_t)(m0 + r_st) * K + k0 + half * 16,
                     AhL, AlL, r_st, half);
      stage_half_row(Wp + (size_t)(n0 + r_st) * K + k0 + half * 16,
                     BhL, BlL, r_st, half);
      __syncthreads();

      short8 ah[4], al[4], bh[4], bl[4];
#pragma unroll
      for (int i = 0; i < 4; ++i) {
        const int ba = lds_addr(wm * 64 + i * 16 + lr, ks * 16);
        ah[i] = *(const short8*)((const char*)AhL + ba);
        al[i] = *(const short8*)((const char*)AlL + ba);
        const int bb_ = lds_addr(wn * 64 + i * 16 + lr, ks * 16);
        bh[i] = *(const short8*)((const char*)BhL + bb_);
        bl[i] = *(const short8*)((const char*)BlL + bb_);
      }
#pragma unroll
      for (int i = 0; i < 4; ++i)
#pragma unroll
        for (int j = 0; j < 4; ++j) {
          acc[i][j] = __builtin_amdgcn_mfma_f32_16x16x32_bf16(ah[i], bh[j], acc[i][j], 0, 0, 0);
          acc[i][j] = __builtin_amdgcn_mfma_f32_16x16x32_bf16(ah[i], bl[j], acc[i][j], 0, 0, 0);
          acc[i][j] = __builtin_amdgcn_mfma_f32_16x16x32_bf16(al[i], bh[j], acc[i][j], 0, 0, 0);
        }
    }
  }

  // epilogue: bias + store. C/D layout: col = lane&15, row = (lane>>4)*4 + reg
  float bias[4];
#pragma unroll
  for (int j = 0; j < 4; ++j) {
    const int col = n0 + wn * 64 + j * 16 + lr;
    bias[j] = b1v[col] + ((n < 8) ? b0v[col] : 0.f);
  }
#pragma unroll
  for (int i = 0; i < 4; ++i) {
    const int grow0 = m0 + wm * 64 + i * 16 + ks * 4;
#pragma unroll
    for (int j = 0; j < 4; ++j) {
      const int col = n0 + wn * 64 + j * 16 + lr;
#pragma unroll
      for (int reg = 0; reg < 4; ++reg)
        G[(size_t)(grow0 + reg) * NG + col] = acc[i][j][reg] + bias[j];
    }
  }
}

// ---------------- persistent GRU recurrence ----------------
__device__ __forceinline__ float sigm(float x) { return 1.f / (1.f + expf(-x)); }

// 256 WGs = 8 batch-groups (8 batches each) x 32 j-blocks (16 j each).
// Per step: uncached h stores -> barrier (vmcnt0 drain) -> lane0 RELEASE
// atomicAdd on the group counter -> lane0 RELAXED poll (s_sleep(8)) until
// ctr == 32*(s+1) -> lane0 ACQUIRE load (L1/L2 inv) -> __syncthreads
// broadcast -> cached coalesced restage. Single poller per WG kills the
// round-3..6 uncached poll storm (32 lanes x 256 WGs on one 1-KB region).
__launch_bounds__(512, 1)
__global__ void gru_persistent(const float* __restrict__ G,
                               const float* __restrict__ Whh,  // [1536][512]
                               const float* __restrict__ bhh,  // [1536]
                               float* __restrict__ out,        // [64][512][512]
                               float* __restrict__ hidden,     // [64][512]
                               int* __restrict__ flags) {      // 8 ctrs, stride 64
  const int wg = blockIdx.x;
  const int bb = wg & 7;         // batch group 0..7  (likely = XCD id)
  const int jb = wg >> 3;        // j block 0..31
  const int tid = threadIdx.x;
  const int j  = tid & 15;
  const int kz = (tid >> 4) & 15;
  const int bh = tid >> 8;

  __shared__ float HX[8][516];          // hx for this group's 8 batches (+pad)
  __shared__ float PART[32 * 196];      // kz-split partial dots

  // ---- register-resident W_hh slice (96 VGPRs/thread) ----
  float wr[32], wi[32], wn[32];
  const int jj = jb * 16 + j;
  {
    const float* pr = Whh + (size_t)jj * Hh + kz * 32;
    const float* pi = Whh + (size_t)(Hh + jj) * Hh + kz * 32;
    const float* pn = Whh + (size_t)(2 * Hh + jj) * Hh + kz * 32;
#pragma unroll
    for (int q = 0; q < 8; ++q) {
      float4 a  = *(const float4*)(pr + q * 4);
      float4 b_ = *(const float4*)(pi + q * 4);
      float4 c  = *(const float4*)(pn + q * 4);
      wr[q*4+0] = a.x;  wr[q*4+1] = a.y;  wr[q*4+2] = a.z;  wr[q*4+3] = a.w;
      wi[q*4+0] = b_.x; wi[q*4+1] = b_.y; wi[q*4+2] = b_.z; wi[q*4+3] = b_.w;
      wn[q*4+0] = c.x;  wn[q*4+1] = c.y;  wn[q*4+2] = c.z;  wn[q*4+3] = c.w;
    }
  }

  // reducer-lane constants (tid<128: rb = local batch, jr = local j)
  const int rb = tid >> 4;
  const int jr = tid & 15;
  const int jjr = jb * 16 + jr;
  float bias_r = 0.f, bias_i = 0.f, bias_n = 0.f;
  if (tid < 128) {
    bias_r = bhh[jjr];
    bias_i = bhh[Hh + jjr];
    bias_n = bhh[2 * Hh + jjr];
  }
  const int slotbase = (bh * 16 + j) * 196;
  int* const ctr = &flags[bb * 64];     // 256-B-padded per-group counter

  for (int s = 0; s < Ss; ++s) {
    // G prefetch for this step (cached; L3 miss hides under the matvec).
    float Gr = 0.f, Gi = 0.f, Gn = 0.f;
    size_t m_pf = 0;
    if (tid < 128) {
      const int gb = bb * 8 + rb;
      m_pf = (size_t)gb * Ss + s;
      Gr = G[m_pf * NG + jjr];
      Gi = G[m_pf * NG + Hh + jjr];
      Gn = G[m_pf * NG + 2 * Hh + jjr];
    }

    float ar[4] = {0, 0, 0, 0}, ai[4] = {0, 0, 0, 0}, an[4] = {0, 0, 0, 0};
    if (s > 0) {
#pragma unroll
      for (int q = 0; q < 8; ++q) {
        const int kk = kz * 32 + q * 4;
#pragma unroll
        for (int b = 0; b < 4; ++b) {
          const float4 h4 = *(const float4*)&HX[bh * 4 + b][kk];
          ar[b] = fmaf(wr[q*4+0], h4.x, ar[b]); ar[b] = fmaf(wr[q*4+1], h4.y, ar[b]);
          ar[b] = fmaf(wr[q*4+2], h4.z, ar[b]); ar[b] = fmaf(wr[q*4+3], h4.w, ar[b]);
          ai[b] = fmaf(wi[q*4+0], h4.x, ai[b]); ai[b] = fmaf(wi[q*4+1], h4.y, ai[b]);
          ai[b] = fmaf(wi[q*4+2], h4.z, ai[b]); ai[b] = fmaf(wi[q*4+3], h4.w, ai[b]);
          an[b] = fmaf(wn[q*4+0], h4.x, an[b]); an[b] = fmaf(wn[q*4+1], h4.y, an[b]);
          an[b] = fmaf(wn[q*4+2], h4.z, an[b]); an[b] = fmaf(wn[q*4+3], h4.w, an[b]);
        }
      }
    }
#pragma unroll
    for (int b = 0; b < 4; ++b) {
      PART[slotbase + (0 * 4 + b) * 16 + kz] = ar[b];
      PART[slotbase + (1 * 4 + b) * 16 + kz] = ai[b];
      PART[slotbase + (2 * 4 + b) * 16 + kz] = an[b];
    }
    __syncthreads();

    if (tid < 128) {
      const int bh_r = rb >> 2, bl_r = rb & 3;
      const int base = (bh_r * 16 + jr) * 196;
      float dr = 0.f, di = 0.f, dn = 0.f;
#pragma unroll
      for (int qq = 0; qq < 4; ++qq) {
        float4 v0 = *(const float4*)&PART[base + (0 * 4 + bl_r) * 16 + qq * 4];
        float4 v1 = *(const float4*)&PART[base + (1 * 4 + bl_r) * 16 + qq * 4];
        float4 v2 = *(const float4*)&PART[base + (2 * 4 + bl_r) * 16 + qq * 4];
        dr += (v0.x + v0.y) + (v0.z + v0.w);
        di += (v1.x + v1.y) + (v1.z + v1.w);
        dn += (v2.x + v2.y) + (v2.z + v2.w);
      }
      const float rg = sigm(Gr + dr + bias_r);
      const float ig = sigm(Gi + di + bias_i);
      const float ng = tanhf(Gn + rg * (dn + bias_n));
      const float hp = (s > 0) ? HX[rb][jjr] : 0.f;
      const float hy = ng + ig * (hp - ng);
      // uncached (agent-scope) store: reaches the coherence point directly.
      __hip_atomic_store(&out[m_pf * Hh + jjr], hy,
                         __ATOMIC_RELAXED, __HIP_MEMORY_SCOPE_AGENT);
      if (s == Ss - 1) hidden[(size_t)(bb * 8 + rb) * Hh + jjr] = hy;
    }
    __syncthreads();   // s_waitcnt vmcnt(0) before s_barrier: h stores drained

    if (s == Ss - 1) break;   // nobody consumes h(511) -> skip final sync

    // ---- per-batch-group sync: ONE poller per WG ----
    if (tid == 0) {
      __hip_atomic_fetch_add(ctr, 1, __ATOMIC_RELEASE, __HIP_MEMORY_SCOPE_AGENT);
      const int target = 32 * (s + 1);
      while (__hip_atomic_load(ctr, __ATOMIC_RELAXED,
                               __HIP_MEMORY_SCOPE_AGENT) < target)
        __builtin_amdgcn_s_sleep(8);
      // ONE acquire: L1/L2 inv so the cached restage refetches fresh lines.
      (void)__hip_atomic_load(ctr, __ATOMIC_ACQUIRE, __HIP_MEMORY_SCOPE_AGENT);
    }
    __syncthreads();   // broadcast "step s visible" to all waves

    // restage hx(s): REGULAR cached loads, 4B/lane fully coalesced (2KB/row).
    {
      const float* srcb = &out[((size_t)(bb * 8) * Ss + s) * Hh + tid];
#pragma unroll
      for (int q = 0; q < 8; ++q)
        HX[q][tid] = srcb[(size_t)q * Ss * Hh];
    }
    __syncthreads();
  }
}

// ---------------------------------------------------------------------------
extern "C" void kernel_launch(void* const* d_in, const int* in_sizes, int n_in,
                              void* d_out, int out_size, void* d_ws, size_t ws_size,
                              hipStream_t stream) {
  const float* feats0 = (const float*)d_in[0];  // [64,512,1536]
  const float* feats1 = (const float*)d_in[1];  // [64,512,2048]
  const float* W0  = (const float*)d_in[2];     // [1024,1536]
  const float* b0  = (const float*)d_in[3];     // [1024]
  const float* W1  = (const float*)d_in[4];     // [1536,2048]
  const float* b1  = (const float*)d_in[5];     // [1536]
  const float* Whh = (const float*)d_in[6];     // [1536,512]
  const float* bhh = (const float*)d_in[7];     // [1536]

  float* out    = (float*)d_out;                    // [64][512][512]
  float* hidden = out + (size_t)Bb * Ss * Hh;       // [64][512]

  char* ws = (char*)d_ws;                           // needs ~202 MB
  float* G   = (float*)(ws + WS_G_OFF);
  int* flags = (int*)(ws + WS_FLAGS_OFF);

  zero_flags_kernel<<<1, 512, 0, stream>>>(flags);

  gemm_G<<<(M_TOT / BM) * (NG / BN), 256, 0, stream>>>(feats1, feats0, W1, W0,
                                                       b1, b0, G);
  gru_persistent<<<256, 512, 0, stream>>>(G, Whh, bhh, out, hidden, flags);
}

// Round 8
// 5494.164 us; speedup vs baseline: 3.9248x; 3.9248x over previous
//
#include <hip/hip_runtime.h>
#include <hip/hip_bf16.h>
#include <stdint.h>

// ---------------------------------------------------------------------------
// Two-stream GRU encoder, MI355X round 8.
//   Phase A (unchanged, ~1.0 ms): split-bf16 3-pass MFMA GEMM (fp32-accurate).
//   Phase B REDESIGN: rounds 3-7 all showed FETCH=28 GB, VGPR=128, dur=20ms.
//     Accounting: 50 MB/step unexplained = 256WG x 512thr x 96 w-floats --
//     the "register-resident" W_hh slice was allocated to SCRATCH (96+~50
//     regs > the allocator's 128-VGPR occupancy target; launch_bounds didn't
//     move it) and reloaded from memory every step. WRITE=185MB confirmed:
//     134 out + 50 scratch-init. FIX: fit UNDER the heuristic -- 48 weights/
//     thread (j=tid&15, kz=tid>>4 in 0..31, 16 k each, all 8 batches/thread,
//     ~100 VGPRs), cross-kz reduce via __shfl_xor butterfly (lanes ^16,^32),
//     16 masked lanes/wave store to 13KB padded PART, 128 reducers sum 8
//     wave-partials. Sync/restage identical to round 7.
// ---------------------------------------------------------------------------

#define Hh 512
#define Bb 64
#define Ss 512
#define M_TOT (Bb * Ss)   // 32768
#define K1d 2048
#define K0d 1536
#define NG 1536           // 3H
#define NF 1024           // 2H

// ---------------- ws layout (bytes) ----------------
#define WS_G_OFF    ((size_t)0)
#define WS_G_BYTES  ((size_t)M_TOT * NG * 4)                 // 201,326,592
#define WS_FLAGS_OFF (WS_G_OFF + WS_G_BYTES)                 // 8 ctrs, 64-int stride

typedef short short8 __attribute__((ext_vector_type(8)));
typedef float f32x4 __attribute__((ext_vector_type(4)));

__global__ void zero_flags_kernel(int* flags) { flags[threadIdx.x] = 0; }

// ---------------- split-bf16 MFMA GEMM ----------------
// 128x128 tile, BK=32, 256 threads (4 waves in 2x2), 4x4 16x16 frags/wave.
#define BM 128
#define BN 128
#define BK 32

// swizzled byte offset inside a [128][32] bf16 tile (row stride 64B):
// addr(r, kbyte) = (r*64 + kbyte) ^ ((r&7)<<4)   — bijective, conflict-free
__device__ __forceinline__ int lds_addr(int r, int kbyte) {
  return ((r << 6) + kbyte) ^ ((r & 7) << 4);
}

// stage 16 consecutive fp32 (one half-row) as bf16 hi/lo into LDS tiles
__device__ __forceinline__ void stage_half_row(const float* __restrict__ src,
                                               ushort* hbuf, ushort* lbuf,
                                               int r, int half) {
#pragma unroll
  for (int q = 0; q < 4; ++q) {
    const float4 v = *(const float4*)(src + q * 4);
    const float e[4] = {v.x, v.y, v.z, v.w};
    ushort4 hv, lv;
    ushort* hp = (ushort*)&hv;
    ushort* lp = (ushort*)&lv;
#pragma unroll
    for (int t = 0; t < 4; ++t) {
      const uint u = __float_as_uint(e[t]);
      const uint hb = u & 0xFFFF0000u;                 // truncated bf16 hi
      const float lf = e[t] - __uint_as_float(hb);     // exact residual
      hp[t] = (ushort)(u >> 16);
      lp[t] = (ushort)(__float_as_uint(lf) >> 16);     // truncated bf16 lo
    }
    const int boff = lds_addr(r, half * 32 + q * 8);
    *(ushort4*)((char*)hbuf + boff) = hv;
    *(ushort4*)((char*)lbuf + boff) = lv;
  }
}

__launch_bounds__(256)
__global__ void gemm_G(const float* __restrict__ A1,   // feats1 [32768][2048]
                       const float* __restrict__ A0,   // feats0 [32768][1536]
                       const float* __restrict__ W1,   // [1536][2048] row-major
                       const float* __restrict__ W0,   // [1024][1536] row-major
                       const float* __restrict__ b1v,
                       const float* __restrict__ b0v,
                       float* __restrict__ G) {
  __shared__ ushort AhL[BM * BK];   // 8 KB each
  __shared__ ushort AlL[BM * BK];
  __shared__ ushort BhL[BN * BK];
  __shared__ ushort BlL[BN * BK];

  // L3 supertile swizzle: 4 groups of 64 m-tiles x 12 n-tiles
  const int bid = blockIdx.x;            // 0..3071
  const int group = bid / 768;
  const int rem = bid - group * 768;
  const int n = rem / 64;                // 0..11
  const int mt = group * 64 + (rem & 63);
  const int m0 = mt * BM, n0 = n * BN;

  const int tid = threadIdx.x;
  const int wid = tid >> 6;              // wave 0..3
  const int wm = wid >> 1, wn = wid & 1; // 2x2 wave grid (64x64 per wave)
  const int lane = tid & 63;
  const int lr = lane & 15;              // frag row/col
  const int ks = lane >> 4;              // k-slot 0..3 (8 bf16 each)

  const int r_st = tid >> 1, half = tid & 1;   // staging map

  f32x4 acc[4][4];
#pragma unroll
  for (int i = 0; i < 4; ++i)
#pragma unroll
    for (int j = 0; j < 4; ++j) acc[i][j] = (f32x4){0.f, 0.f, 0.f, 0.f};

  const int nph = (n < 8) ? 2 : 1;       // n>=8 -> pure i_n cols (no feats0 term)

  for (int p = 0; p < nph; ++p) {
    const float* Ap = (p == 0) ? A1 : A0;
    const float* Wp = (p == 0) ? W1 : W0;
    const int K = (p == 0) ? K1d : K0d;

    for (int k0 = 0; k0 < K; k0 += BK) {
      __syncthreads();
      stage_half_row(Ap + (size_t)(m0 + r_st) * K + k0 + half * 16,
                     AhL, AlL, r_st, half);
      stage_half_row(Wp + (size_t)(n0 + r_st) * K + k0 + half * 16,
                     BhL, BlL, r_st, half);
      __syncthreads();

      short8 ah[4], al[4], bh[4], bl[4];
#pragma unroll
      for (int i = 0; i < 4; ++i) {
        const int ba = lds_addr(wm * 64 + i * 16 + lr, ks * 16);
        ah[i] = *(const short8*)((const char*)AhL + ba);
        al[i] = *(const short8*)((const char*)AlL + ba);
        const int bb_ = lds_addr(wn * 64 + i * 16 + lr, ks * 16);
        bh[i] = *(const short8*)((const char*)BhL + bb_);
        bl[i] = *(const short8*)((const char*)BlL + bb_);
      }
#pragma unroll
      for (int i = 0; i < 4; ++i)
#pragma unroll
        for (int j = 0; j < 4; ++j) {
          acc[i][j] = __builtin_amdgcn_mfma_f32_16x16x32_bf16(ah[i], bh[j], acc[i][j], 0, 0, 0);
          acc[i][j] = __builtin_amdgcn_mfma_f32_16x16x32_bf16(ah[i], bl[j], acc[i][j], 0, 0, 0);
          acc[i][j] = __builtin_amdgcn_mfma_f32_16x16x32_bf16(al[i], bh[j], acc[i][j], 0, 0, 0);
        }
    }
  }

  // epilogue: bias + store. C/D layout: col = lane&15, row = (lane>>4)*4 + reg
  float bias[4];
#pragma unroll
  for (int j = 0; j < 4; ++j) {
    const int col = n0 + wn * 64 + j * 16 + lr;
    bias[j] = b1v[col] + ((n < 8) ? b0v[col] : 0.f);
  }
#pragma unroll
  for (int i = 0; i < 4; ++i) {
    const int grow0 = m0 + wm * 64 + i * 16 + ks * 4;
#pragma unroll
    for (int j = 0; j < 4; ++j) {
      const int col = n0 + wn * 64 + j * 16 + lr;
#pragma unroll
      for (int reg = 0; reg < 4; ++reg)
        G[(size_t)(grow0 + reg) * NG + col] = acc[i][j][reg] + bias[j];
    }
  }
}

// ---------------- persistent GRU recurrence ----------------
__device__ __forceinline__ float sigm(float x) { return 1.f / (1.f + expf(-x)); }

// PART layout: [g(3)][b(8)][w(8)][j(16)+pad] — j contiguous (conflict-free
// stores), w-stride 17 words (odd) so reducer lanes spread banks.
#define PIDX(g, b, w, j) ((((g) * 8 + (b)) * 8 + (w)) * 17 + (j))

// 256 WGs = 8 batch-groups (8 batches each) x 32 j-blocks (16 j each).
// Thread map: j = tid&15, kz = tid>>4 (0..31; k in [kz*16, kz*16+16)).
// 48 weights/thread in VGPRs (3 gates x 16 k) + 24 batch-accumulators
// ~= 100 VGPRs total: fits UNDER the allocator's 128 target (rounds 3-7
// proved 96+50 does not -> scratch reload = 50 MB/step = the 28 GB FETCH).
// Cross-kz reduce: __shfl_xor ^16/^32 butterfly (those lanes share j),
// then 16 masked lanes/wave store per-wave partials; 128 reducers finish.
__launch_bounds__(512)
__global__ void gru_persistent(const float* __restrict__ G,
                               const float* __restrict__ Whh,  // [1536][512]
                               const float* __restrict__ bhh,  // [1536]
                               float* __restrict__ out,        // [64][512][512]
                               float* __restrict__ hidden,     // [64][512]
                               int* __restrict__ flags) {      // 8 ctrs, stride 64
  const int wg = blockIdx.x;
  const int bb = wg & 7;         // batch group 0..7  (likely = XCD id)
  const int jb = wg >> 3;        // j block 0..31
  const int tid = threadIdx.x;
  const int j  = tid & 15;
  const int kz = tid >> 4;       // 0..31
  const int w  = tid >> 6;       // wave 0..7
  const int sg = (tid >> 4) & 3; // kz sub-slot within wave

  __shared__ float HX[8][516];   // hx for this group's 8 batches (+pad) 16.5KB
  __shared__ float PART[3264];   // per-wave partials, padded           13  KB

  // ---- register-resident W_hh slice: 48 VGPRs/thread ----
  float wr[16], wi[16], wn[16];
  const int jj = jb * 16 + j;
  {
    const float* pr = Whh + (size_t)jj * Hh + kz * 16;
    const float* pi = Whh + (size_t)(Hh + jj) * Hh + kz * 16;
    const float* pn = Whh + (size_t)(2 * Hh + jj) * Hh + kz * 16;
#pragma unroll
    for (int q = 0; q < 4; ++q) {
      const float4 a  = *(const float4*)(pr + q * 4);
      const float4 b_ = *(const float4*)(pi + q * 4);
      const float4 c  = *(const float4*)(pn + q * 4);
      wr[q*4+0] = a.x;  wr[q*4+1] = a.y;  wr[q*4+2] = a.z;  wr[q*4+3] = a.w;
      wi[q*4+0] = b_.x; wi[q*4+1] = b_.y; wi[q*4+2] = b_.z; wi[q*4+3] = b_.w;
      wn[q*4+0] = c.x;  wn[q*4+1] = c.y;  wn[q*4+2] = c.z;  wn[q*4+3] = c.w;
    }
  }

  // reducer-lane constants (tid<128: rb = local batch 0..7, jr = local j)
  const int rb = tid >> 4;
  const int jr = tid & 15;
  const int jjr = jb * 16 + jr;
  float bias_r = 0.f, bias_i = 0.f, bias_n = 0.f;
  if (tid < 128) {
    bias_r = bhh[jjr];
    bias_i = bhh[Hh + jjr];
    bias_n = bhh[2 * Hh + jjr];
  }

  int* const ctr = &flags[bb * 64];     // 256-B-padded per-group counter

  for (int s = 0; s < Ss; ++s) {
    // G prefetch for this step (cached; hides under the matvec).
    float Gr = 0.f, Gi = 0.f, Gn = 0.f;
    size_t m_pf = 0;
    if (tid < 128) {
      const int gb = bb * 8 + rb;
      m_pf = (size_t)gb * Ss + s;
      Gr = G[m_pf * NG + jjr];
      Gi = G[m_pf * NG + Hh + jjr];
      Gn = G[m_pf * NG + 2 * Hh + jjr];
    }

    // ---- matvec: 48 weights x 8 batches = 384 FMA/thread ----
    float ar[8] = {0,0,0,0,0,0,0,0};
    float ai[8] = {0,0,0,0,0,0,0,0};
    float an[8] = {0,0,0,0,0,0,0,0};
    if (s > 0) {
#pragma unroll
      for (int b = 0; b < 8; ++b) {
#pragma unroll
        for (int q = 0; q < 4; ++q) {
          const float4 h4 = *(const float4*)&HX[b][kz * 16 + q * 4];
          ar[b] = fmaf(wr[q*4+0], h4.x, ar[b]); ar[b] = fmaf(wr[q*4+1], h4.y, ar[b]);
          ar[b] = fmaf(wr[q*4+2], h4.z, ar[b]); ar[b] = fmaf(wr[q*4+3], h4.w, ar[b]);
          ai[b] = fmaf(wi[q*4+0], h4.x, ai[b]); ai[b] = fmaf(wi[q*4+1], h4.y, ai[b]);
          ai[b] = fmaf(wi[q*4+2], h4.z, ai[b]); ai[b] = fmaf(wi[q*4+3], h4.w, ai[b]);
          an[b] = fmaf(wn[q*4+0], h4.x, an[b]); an[b] = fmaf(wn[q*4+1], h4.y, an[b]);
          an[b] = fmaf(wn[q*4+2], h4.z, an[b]); an[b] = fmaf(wn[q*4+3], h4.w, an[b]);
        }
      }
    }

    // ---- cross-kz butterfly: lanes ^16 and ^32 share j, differ in kz ----
#pragma unroll
    for (int b = 0; b < 8; ++b) {
      ar[b] += __shfl_xor(ar[b], 16, 64); ar[b] += __shfl_xor(ar[b], 32, 64);
      ai[b] += __shfl_xor(ai[b], 16, 64); ai[b] += __shfl_xor(ai[b], 32, 64);
      an[b] += __shfl_xor(an[b], 16, 64); an[b] += __shfl_xor(an[b], 32, 64);
    }
    // 24 (g,b) sums per (j, wave); subgroup sg stores its 6 (exec-masked).
#pragma unroll
    for (int v = 0; v < 24; ++v) {
      if ((v / 6) == sg) {
        const int g = v >> 3, b = v & 7;
        const float val = (g == 0) ? ar[b] : ((g == 1) ? ai[b] : an[b]);
        PART[PIDX(g, b, w, j)] = val;
      }
    }
    __syncthreads();

    if (tid < 128) {
      float dr = 0.f, di = 0.f, dn = 0.f;
#pragma unroll
      for (int w2 = 0; w2 < 8; ++w2) {
        dr += PART[PIDX(0, rb, w2, jr)];
        di += PART[PIDX(1, rb, w2, jr)];
        dn += PART[PIDX(2, rb, w2, jr)];
      }
      const float rg = sigm(Gr + dr + bias_r);
      const float ig = sigm(Gi + di + bias_i);
      const float ng = tanhf(Gn + rg * (dn + bias_n));
      const float hp = (s > 0) ? HX[rb][jjr] : 0.f;
      const float hy = ng + ig * (hp - ng);
      // uncached (agent-scope) store: reaches the coherence point directly.
      __hip_atomic_store(&out[m_pf * Hh + jjr], hy,
                         __ATOMIC_RELAXED, __HIP_MEMORY_SCOPE_AGENT);
      if (s == Ss - 1) hidden[(size_t)(bb * 8 + rb) * Hh + jjr] = hy;
    }
    __syncthreads();   // s_waitcnt vmcnt(0) before s_barrier: h stores drained

    if (s == Ss - 1) break;   // nobody consumes h(511) -> skip final sync

    // ---- per-batch-group sync: ONE poller per WG ----
    if (tid == 0) {
      __hip_atomic_fetch_add(ctr, 1, __ATOMIC_RELEASE, __HIP_MEMORY_SCOPE_AGENT);
      const int target = 32 * (s + 1);
      while (__hip_atomic_load(ctr, __ATOMIC_RELAXED,
                               __HIP_MEMORY_SCOPE_AGENT) < target)
        __builtin_amdgcn_s_sleep(8);
      // ONE acquire: L1/L2 inv so the cached restage refetches fresh lines.
      (void)__hip_atomic_load(ctr, __ATOMIC_ACQUIRE, __HIP_MEMORY_SCOPE_AGENT);
    }
    __syncthreads();   // broadcast "step s visible" to all waves

    // restage hx(s): REGULAR cached loads, 4B/lane fully coalesced (2KB/row).
    {
      const float* srcb = &out[((size_t)(bb * 8) * Ss + s) * Hh + tid];
#pragma unroll
      for (int q = 0; q < 8; ++q)
        HX[q][tid] = srcb[(size_t)q * Ss * Hh];
    }
    __syncthreads();
  }
}

// ---------------------------------------------------------------------------
extern "C" void kernel_launch(void* const* d_in, const int* in_sizes, int n_in,
                              void* d_out, int out_size, void* d_ws, size_t ws_size,
                              hipStream_t stream) {
  const float* feats0 = (const float*)d_in[0];  // [64,512,1536]
  const float* feats1 = (const float*)d_in[1];  // [64,512,2048]
  const float* W0  = (const float*)d_in[2];     // [1024,1536]
  const float* b0  = (const float*)d_in[3];     // [1024]
  const float* W1  = (const float*)d_in[4];     // [1536,2048]
  const float* b1  = (const float*)d_in[5];     // [1536]
  const float* Whh = (const float*)d_in[6];     // [1536,512]
  const float* bhh = (const float*)d_in[7];     // [1536]

  float* out    = (float*)d_out;                    // [64][512][512]
  float* hidden = out + (size_t)Bb * Ss * Hh;       // [64][512]

  char* ws = (char*)d_ws;                           // needs ~202 MB
  float* G   = (float*)(ws + WS_G_OFF);
  int* flags = (int*)(ws + WS_FLAGS_OFF);

  zero_flags_kernel<<<1, 512, 0, stream>>>(flags);

  gemm_G<<<(M_TOT / BM) * (NG / BN), 256, 0, stream>>>(feats1, feats0, W1, W0,
                                                       b1, b0, G);
  gru_persistent<<<256, 512, 0, stream>>>(G, Whh, bhh, out, hidden, flags);
}